// Round 1
// baseline (1991.924 us; speedup 1.0000x reference)
//
#include <hip/hip_runtime.h>
#include <hip/hip_bf16.h>
#include <math.h>

// Problem constants: B=2, S=T=2048, E=1024, H=16, D=64
#define GBM 64
#define GBN 64
#define GBK 32

// C[M,N] = A[M,K] @ W[N,K]^T + bias[N]   (all fp32, row-major)
__global__ __launch_bounds__(256) void gemm_nt_bias_f32(
    const float* __restrict__ A,
    const float* __restrict__ W,
    const float* __restrict__ bias,
    float* __restrict__ C,
    int M, int N, int K)
{
    __shared__ float As[GBK][GBM + 4];
    __shared__ float Bs[GBK][GBN + 4];
    const int tid = threadIdx.x;
    const int bm = blockIdx.y * GBM;
    const int bn = blockIdx.x * GBN;
    const int ty = tid >> 4;   // 0..15: row group (4 rows each)
    const int tx = tid & 15;   // 0..15: col group (4 cols each)

    float4 acc[4];
#pragma unroll
    for (int i = 0; i < 4; ++i) acc[i] = make_float4(0.f, 0.f, 0.f, 0.f);

    for (int k0 = 0; k0 < K; k0 += GBK) {
        // Stage tiles: 64 rows x 32 k-cols = 512 float4 per tile; 2 per thread.
#pragma unroll
        for (int t = 0; t < 2; ++t) {
            const int idx = tid + t * 256;
            const int row = idx >> 3;          // 0..63
            const int c4  = (idx & 7) << 2;    // 0,4,...,28
            const float4 av = *(const float4*)(A + (size_t)(bm + row) * K + k0 + c4);
            As[c4 + 0][row] = av.x;
            As[c4 + 1][row] = av.y;
            As[c4 + 2][row] = av.z;
            As[c4 + 3][row] = av.w;
            const float4 wv = *(const float4*)(W + (size_t)(bn + row) * K + k0 + c4);
            Bs[c4 + 0][row] = wv.x;
            Bs[c4 + 1][row] = wv.y;
            Bs[c4 + 2][row] = wv.z;
            Bs[c4 + 3][row] = wv.w;
        }
        __syncthreads();
#pragma unroll
        for (int k = 0; k < GBK; ++k) {
            const float4 a = *(const float4*)&As[k][ty << 2];
            const float4 b = *(const float4*)&Bs[k][tx << 2];
            acc[0].x += a.x * b.x; acc[0].y += a.x * b.y; acc[0].z += a.x * b.z; acc[0].w += a.x * b.w;
            acc[1].x += a.y * b.x; acc[1].y += a.y * b.y; acc[1].z += a.y * b.z; acc[1].w += a.y * b.w;
            acc[2].x += a.z * b.x; acc[2].y += a.z * b.y; acc[2].z += a.z * b.z; acc[2].w += a.z * b.w;
            acc[3].x += a.w * b.x; acc[3].y += a.w * b.y; acc[3].z += a.w * b.z; acc[3].w += a.w * b.w;
        }
        __syncthreads();
    }

    const float4 bb = *(const float4*)(bias + bn + (tx << 2));
#pragma unroll
    for (int i = 0; i < 4; ++i) {
        float4 c = acc[i];
        c.x += bb.x; c.y += bb.y; c.z += bb.z; c.w += bb.w;
        *(float4*)(C + (size_t)(bm + (ty << 2) + i) * N + bn + (tx << 2)) = c;
    }
}

// Flash attention fp32. Layout of Q/K/V buffers: [B, S, H*D] = [B, S, 1024],
// head h occupies columns h*64 .. h*64+63.
// Block: 256 threads handle one (b, h, 64-row Q tile).
// Thread (r = tid>>2, q = tid&3): owns score cols q*16..q*16+15 and
// output dims q*16..q*16+15 of row r.
__global__ __launch_bounds__(256) void flash_attn_f32(
    const float* __restrict__ Qb, const float* __restrict__ Kb,
    const float* __restrict__ Vb, float* __restrict__ Ob)
{
    __shared__ float Ks[64][72];
    __shared__ float Vs[64][72];
    __shared__ float Ps[64][68];

    const int tid = threadIdx.x;
    const int r = tid >> 2;
    const int q = tid & 3;
    const int s0 = blockIdx.x << 6;
    const int h = blockIdx.y;
    const int b = blockIdx.z;
    const size_t base = ((size_t)b * 2048) * 1024 + (size_t)h * 64;

    // Q row r cached in registers (64 floats).
    float4 qreg[16];
    {
        const float* qrow = Qb + base + (size_t)(s0 + r) * 1024;
#pragma unroll
        for (int i = 0; i < 16; ++i) qreg[i] = *(const float4*)(qrow + i * 4);
    }

    float m_run = -3.0e38f;
    float l_run = 0.f;
    float4 acc[4];
#pragma unroll
    for (int i = 0; i < 4; ++i) acc[i] = make_float4(0.f, 0.f, 0.f, 0.f);

    for (int t0 = 0; t0 < 2048; t0 += 64) {
        // Stage K and V tiles (64x64 each): 4 float4 per thread per tile.
#pragma unroll
        for (int i = 0; i < 4; ++i) {
            const int idx = tid + i * 256;
            const int row = idx >> 4;          // 0..63
            const int col = (idx & 15) << 2;   // 0..60
            *(float4*)&Ks[row][col] = *(const float4*)(Kb + base + (size_t)(t0 + row) * 1024 + col);
            *(float4*)&Vs[row][col] = *(const float4*)(Vb + base + (size_t)(t0 + row) * 1024 + col);
        }
        __syncthreads();

        // Scores: s[j] = (Q[r] . K[c]) / 8,  c = q*16+j
        float s[16];
#pragma unroll
        for (int j = 0; j < 16; ++j) {
            const int c = (q << 4) + j;
            float sum = 0.f;
#pragma unroll
            for (int k4i = 0; k4i < 16; ++k4i) {
                const int k4 = k4i ^ (q << 2);  // phase by q: kills 4-way LDS conflict
                const float4 kv = *(const float4*)&Ks[c][k4 << 2];
                const float4 qv = qreg[k4];
                sum += qv.x * kv.x + qv.y * kv.y + qv.z * kv.z + qv.w * kv.w;
            }
            s[j] = sum * 0.125f;
        }

        // Online softmax (rows span 4 consecutive lanes: tid = 4*r + q)
        float mt = s[0];
#pragma unroll
        for (int j = 1; j < 16; ++j) mt = fmaxf(mt, s[j]);
        mt = fmaxf(mt, __shfl_xor(mt, 1));
        mt = fmaxf(mt, __shfl_xor(mt, 2));
        const float m_new = fmaxf(m_run, mt);
        const float alpha = __expf(m_run - m_new);
        float lsum = 0.f;
#pragma unroll
        for (int j = 0; j < 16; ++j) {
            const float p = __expf(s[j] - m_new);
            s[j] = p;
            lsum += p;
        }
        lsum += __shfl_xor(lsum, 1);
        lsum += __shfl_xor(lsum, 2);
        l_run = l_run * alpha + lsum;
        m_run = m_new;
#pragma unroll
        for (int i = 0; i < 4; ++i) {
            acc[i].x *= alpha; acc[i].y *= alpha; acc[i].z *= alpha; acc[i].w *= alpha;
        }

        // Publish P tile
#pragma unroll
        for (int j = 0; j < 16; j += 4) {
            const float4 pv = make_float4(s[j], s[j + 1], s[j + 2], s[j + 3]);
            *(float4*)&Ps[r][(q << 4) + j] = pv;
        }
        __syncthreads();

        // O[r][q*16 .. q*16+15] += sum_c P[r][c] * V[c][...]
        for (int c = 0; c < 64; ++c) {
            const float p = Ps[r][c];
#pragma unroll
            for (int j4 = 0; j4 < 4; ++j4) {
                const float4 vv = *(const float4*)&Vs[c][(q << 4) + (j4 << 2)];
                acc[j4].x += p * vv.x;
                acc[j4].y += p * vv.y;
                acc[j4].z += p * vv.z;
                acc[j4].w += p * vv.w;
            }
        }
        __syncthreads();
    }

    const float inv_l = 1.f / l_run;
    float* orow = Ob + base + (size_t)(s0 + r) * 1024 + (q << 4);
#pragma unroll
    for (int j4 = 0; j4 < 4; ++j4) {
        float4 o;
        o.x = acc[j4].x * inv_l;
        o.y = acc[j4].y * inv_l;
        o.z = acc[j4].z * inv_l;
        o.w = acc[j4].w * inv_l;
        *(float4*)(orow + (j4 << 2)) = o;
    }
}

extern "C" void kernel_launch(void* const* d_in, const int* in_sizes, int n_in,
                              void* d_out, int out_size, void* d_ws, size_t ws_size,
                              hipStream_t stream)
{
    // setup_inputs() order: query, value, key, Wq, bq, Wk, bk, Wv, bv, Wo, bo
    const float* query = (const float*)d_in[0];
    const float* value = (const float*)d_in[1];
    const float* key   = (const float*)d_in[2];
    const float* Wq = (const float*)d_in[3];
    const float* bq = (const float*)d_in[4];
    const float* Wk = (const float*)d_in[5];
    const float* bk = (const float*)d_in[6];
    const float* Wv = (const float*)d_in[7];
    const float* bv = (const float*)d_in[8];
    const float* Wo = (const float*)d_in[9];
    const float* bo = (const float*)d_in[10];
    float* out = (float*)d_out;

    const int M = 2 * 2048;   // B*S
    const int E = 1024;
    const size_t elems = (size_t)M * E;

    float* Qb = (float*)d_ws;
    float* Kb = Qb + elems;
    float* Vb = Kb + elems;
    float* Ab = Vb + elems;   // attention output, pre-Wo

    dim3 gblk(256);
    dim3 ggrid(E / GBN, M / GBM);
    hipLaunchKernelGGL(gemm_nt_bias_f32, ggrid, gblk, 0, stream, query, Wq, bq, Qb, M, E, E);
    hipLaunchKernelGGL(gemm_nt_bias_f32, ggrid, gblk, 0, stream, key,   Wk, bk, Kb, M, E, E);
    hipLaunchKernelGGL(gemm_nt_bias_f32, ggrid, gblk, 0, stream, value, Wv, bv, Vb, M, E, E);

    dim3 fgrid(2048 / 64, 16, 2);
    hipLaunchKernelGGL(flash_attn_f32, fgrid, gblk, 0, stream, Qb, Kb, Vb, Ab);

    hipLaunchKernelGGL(gemm_nt_bias_f32, ggrid, gblk, 0, stream, Ab, Wo, bo, out, M, E, E);
}

// Round 2
// 654.134 us; speedup vs baseline: 3.0451x; 3.0451x over previous
//
#include <hip/hip_runtime.h>
#include <math.h>

// Problem constants: B=2, S=T=2048, E=1024, H=16, D=64
#define GBM 64
#define GBN 64
#define GBK 32

typedef __attribute__((ext_vector_type(8))) short short8;
typedef __attribute__((ext_vector_type(4))) float f32x4;
typedef unsigned short u16;

// fp32 -> bf16 round-to-nearest-even (finite inputs)
__device__ __forceinline__ u16 f2bf(float x) {
    unsigned int u = __float_as_uint(x);
    u += 0x7FFFu + ((u >> 16) & 1u);
    return (u16)(u >> 16);
}

// C[M,N] = A[M,K] @ W[N,K]^T + bias[N]  (fp32 compute; output fp32 or bf16)
template <bool BF16OUT>
__global__ __launch_bounds__(256) void gemm_nt_bias(
    const float* __restrict__ A,
    const float* __restrict__ W,
    const float* __restrict__ bias,
    void* __restrict__ Cout,
    int M, int N, int K)
{
    __shared__ float As[GBK][GBM + 4];
    __shared__ float Bs[GBK][GBN + 4];
    const int tid = threadIdx.x;
    const int bm = blockIdx.y * GBM;
    const int bn = blockIdx.x * GBN;
    const int ty = tid >> 4;
    const int tx = tid & 15;

    float4 acc[4];
#pragma unroll
    for (int i = 0; i < 4; ++i) acc[i] = make_float4(0.f, 0.f, 0.f, 0.f);

    for (int k0 = 0; k0 < K; k0 += GBK) {
#pragma unroll
        for (int t = 0; t < 2; ++t) {
            const int idx = tid + t * 256;
            const int row = idx >> 3;
            const int c4  = (idx & 7) << 2;
            const float4 av = *(const float4*)(A + (size_t)(bm + row) * K + k0 + c4);
            As[c4 + 0][row] = av.x;
            As[c4 + 1][row] = av.y;
            As[c4 + 2][row] = av.z;
            As[c4 + 3][row] = av.w;
            const float4 wv = *(const float4*)(W + (size_t)(bn + row) * K + k0 + c4);
            Bs[c4 + 0][row] = wv.x;
            Bs[c4 + 1][row] = wv.y;
            Bs[c4 + 2][row] = wv.z;
            Bs[c4 + 3][row] = wv.w;
        }
        __syncthreads();
#pragma unroll
        for (int k = 0; k < GBK; ++k) {
            const float4 a = *(const float4*)&As[k][ty << 2];
            const float4 b = *(const float4*)&Bs[k][tx << 2];
            acc[0].x += a.x * b.x; acc[0].y += a.x * b.y; acc[0].z += a.x * b.z; acc[0].w += a.x * b.w;
            acc[1].x += a.y * b.x; acc[1].y += a.y * b.y; acc[1].z += a.y * b.z; acc[1].w += a.y * b.w;
            acc[2].x += a.z * b.x; acc[2].y += a.z * b.y; acc[2].z += a.z * b.z; acc[2].w += a.z * b.w;
            acc[3].x += a.w * b.x; acc[3].y += a.w * b.y; acc[3].z += a.w * b.z; acc[3].w += a.w * b.w;
        }
        __syncthreads();
    }

    const float4 bb = *(const float4*)(bias + bn + (tx << 2));
#pragma unroll
    for (int i = 0; i < 4; ++i) {
        float4 c = acc[i];
        c.x += bb.x; c.y += bb.y; c.z += bb.z; c.w += bb.w;
        const size_t off = (size_t)(bm + (ty << 2) + i) * N + bn + (tx << 2);
        if (BF16OUT) {
            ushort4 o;
            o.x = f2bf(c.x); o.y = f2bf(c.y); o.z = f2bf(c.z); o.w = f2bf(c.w);
            *(ushort4*)((u16*)Cout + off) = o;
        } else {
            *(float4*)((float*)Cout + off) = c;
        }
    }
}

// -----------------------------------------------------------------------------
// MFMA flash attention (bf16 inputs, fp32 accumulate, fp32 output).
// Q/K/V layout: [B, S, H*D] bf16; head h = columns h*64 .. h*64+63.
// Block = 256 threads = 4 waves. Q tile = 64 rows (16/wave). KV tile = 64.
// mfma_f32_16x16x32_bf16:
//   A frag: row = lane&15,          k = (lane>>4)*8 + j   (8 contiguous bf16)
//   B frag: col = lane&15,          k = (lane>>4)*8 + j
//   C/D   : col = lane&15,          row = (lane>>4)*4 + reg   [HW-verified]
// LDS: Ks[key][d] (XOR swz f=key&7), Vt[d][key] (f=(d&7)^(d>>3)),
//      Ps[wave][q][key] (f=q&7). All swizzles XOR bits 3..5 of the u16 index
//      (= byte bits 4..6), preserving 16B alignment of b128 accesses.
// -----------------------------------------------------------------------------
__global__ __launch_bounds__(256) void flash_attn_mfma(
    const u16* __restrict__ Qb, const u16* __restrict__ Kb,
    const u16* __restrict__ Vb, float* __restrict__ Ob)
{
    __shared__ u16 Ks[64 * 64];
    __shared__ u16 Vt[64 * 64];
    __shared__ u16 Ps[4][16 * 64];

    const int tid = threadIdx.x;
    const int w  = tid >> 6;
    const int l  = tid & 63;
    const int l4 = l >> 4;     // 0..3
    const int lm = l & 15;     // 0..15
    const int s0 = blockIdx.x << 6;
    const int h  = blockIdx.y;
    const int b  = blockIdx.z;
    const size_t bbase = (size_t)b * 2048 * 1024 + (size_t)h * 64;

    // Q fragments (A-operand), cached in registers for the whole kernel.
    short8 qf[2];
    {
        const u16* qrow = Qb + bbase + (size_t)(s0 + w * 16 + lm) * 1024;
        qf[0] = *(const short8*)(qrow + l4 * 8);
        qf[1] = *(const short8*)(qrow + 32 + l4 * 8);
    }

    f32x4 oacc[4];
#pragma unroll
    for (int g = 0; g < 4; ++g) oacc[g] = (f32x4){0.f, 0.f, 0.f, 0.f};
    float m_run[4] = {-1e30f, -1e30f, -1e30f, -1e30f};
    float l_run[4] = {0.f, 0.f, 0.f, 0.f};

    for (int t0 = 0; t0 < 2048; t0 += 64) {
        __syncthreads();   // everyone done reading previous K/V
        // ---- stage K tile [key][d] and V tile transposed [d][key] ----
#pragma unroll
        for (int n = 0; n < 2; ++n) {
            const int idx = tid + (n << 8);
            const int row = idx >> 3;           // 0..63 (token within tile)
            const int c8  = (idx & 7) << 3;     // 0,8,...,56 (dim start)
            const short8 kv = *(const short8*)(Kb + bbase + (size_t)(t0 + row) * 1024 + c8);
            *(short8*)&Ks[(row * 64 + c8) ^ ((row & 7) << 3)] = kv;
            const short8 vv = *(const short8*)(Vb + bbase + (size_t)(t0 + row) * 1024 + c8);
            const u16* vs = (const u16*)&vv;
#pragma unroll
            for (int j = 0; j < 8; ++j) {
                const int d = c8 + j;
                Vt[(d * 64 + row) ^ ((((d & 7) ^ (d >> 3))) << 3)] = vs[j];
            }
        }
        __syncthreads();   // staging complete

        // ---- QK^T: C[q][key], q rows of this wave ----
        f32x4 sacc[4];
#pragma unroll
        for (int g = 0; g < 4; ++g) sacc[g] = (f32x4){0.f, 0.f, 0.f, 0.f};
#pragma unroll
        for (int g = 0; g < 4; ++g) {
            const int key = lm + 16 * g;
#pragma unroll
            for (int c = 0; c < 2; ++c) {
                const short8 kf = *(const short8*)&Ks[(key * 64 + c * 32 + l4 * 8) ^ ((key & 7) << 3)];
                sacc[g] = __builtin_amdgcn_mfma_f32_16x16x32_bf16(qf[c], kf, sacc[g], 0, 0, 0);
            }
        }

        // ---- online softmax (row q = l4*4 + r; reduce over g and lanes lm) ----
#pragma unroll
        for (int r = 0; r < 4; ++r) {
            float mt = fmaxf(fmaxf(sacc[0][r], sacc[1][r]), fmaxf(sacc[2][r], sacc[3][r]));
            mt = fmaxf(mt, __shfl_xor(mt, 1));
            mt = fmaxf(mt, __shfl_xor(mt, 2));
            mt = fmaxf(mt, __shfl_xor(mt, 4));
            mt = fmaxf(mt, __shfl_xor(mt, 8));
            const float m_new = fmaxf(m_run[r], mt);
            const float alpha = __expf((m_run[r] - m_new) * 0.125f);
            float p[4];
            float ls = 0.f;
#pragma unroll
            for (int g = 0; g < 4; ++g) {
                p[g] = __expf((sacc[g][r] - m_new) * 0.125f);
                ls += p[g];
            }
            const int q = l4 * 4 + r;
#pragma unroll
            for (int g = 0; g < 4; ++g)
                Ps[w][(q * 64 + lm + 16 * g) ^ ((q & 7) << 3)] = f2bf(p[g]);
            ls += __shfl_xor(ls, 1);
            ls += __shfl_xor(ls, 2);
            ls += __shfl_xor(ls, 4);
            ls += __shfl_xor(ls, 8);
            l_run[r] = l_run[r] * alpha + ls;
            m_run[r] = m_new;
#pragma unroll
            for (int g = 0; g < 4; ++g) oacc[g][r] *= alpha;
        }

        // ---- PV: O[q][d] += P[q][key] * V[key][d]  (P is per-wave private) ----
#pragma unroll
        for (int c = 0; c < 2; ++c) {
            const short8 pa = *(const short8*)&Ps[w][(lm * 64 + c * 32 + l4 * 8) ^ ((lm & 7) << 3)];
#pragma unroll
            for (int g = 0; g < 4; ++g) {
                const int d = lm + 16 * g;
                const short8 vf = *(const short8*)&Vt[(d * 64 + c * 32 + l4 * 8) ^ (((d & 7) ^ (d >> 3)) << 3)];
                oacc[g] = __builtin_amdgcn_mfma_f32_16x16x32_bf16(pa, vf, oacc[g], 0, 0, 0);
            }
        }
    }

    // ---- epilogue: normalize and store fp32 ----
#pragma unroll
    for (int r = 0; r < 4; ++r) {
        const float inv = 1.f / l_run[r];
        const size_t qrow = (size_t)(s0 + w * 16 + l4 * 4 + r) * 1024;
#pragma unroll
        for (int g = 0; g < 4; ++g)
            Ob[bbase + qrow + lm + 16 * g] = oacc[g][r] * inv;
    }
}

extern "C" void kernel_launch(void* const* d_in, const int* in_sizes, int n_in,
                              void* d_out, int out_size, void* d_ws, size_t ws_size,
                              hipStream_t stream)
{
    // setup_inputs() order: query, value, key, Wq, bq, Wk, bk, Wv, bv, Wo, bo
    const float* query = (const float*)d_in[0];
    const float* value = (const float*)d_in[1];
    const float* key   = (const float*)d_in[2];
    const float* Wq = (const float*)d_in[3];
    const float* bq = (const float*)d_in[4];
    const float* Wk = (const float*)d_in[5];
    const float* bk = (const float*)d_in[6];
    const float* Wv = (const float*)d_in[7];
    const float* bv = (const float*)d_in[8];
    const float* Wo = (const float*)d_in[9];
    const float* bo = (const float*)d_in[10];
    float* out = (float*)d_out;

    const int M = 2 * 2048;
    const int E = 1024;
    const size_t elems = (size_t)M * E;

    u16* Qb = (u16*)d_ws;
    u16* Kb = Qb + elems;
    u16* Vb = Kb + elems;
    float* Ab = (float*)(Vb + elems);

    dim3 gblk(256);
    dim3 ggrid(E / GBN, M / GBM);
    hipLaunchKernelGGL((gemm_nt_bias<true>),  ggrid, gblk, 0, stream, query, Wq, bq, (void*)Qb, M, E, E);
    hipLaunchKernelGGL((gemm_nt_bias<true>),  ggrid, gblk, 0, stream, key,   Wk, bk, (void*)Kb, M, E, E);
    hipLaunchKernelGGL((gemm_nt_bias<true>),  ggrid, gblk, 0, stream, value, Wv, bv, (void*)Vb, M, E, E);

    dim3 fgrid(2048 / 64, 16, 2);
    hipLaunchKernelGGL(flash_attn_mfma, fgrid, gblk, 0, stream, Qb, Kb, Vb, Ab);

    hipLaunchKernelGGL((gemm_nt_bias<false>), ggrid, gblk, 0, stream, Ab, Wo, bo, (void*)out, M, E, E);
}

// Round 3
// 225.028 us; speedup vs baseline: 8.8519x; 2.9069x over previous
//
#include <hip/hip_runtime.h>
#include <math.h>

// Problem constants: B=2, S=T=2048, E=1024, H=16, D=64
typedef __attribute__((ext_vector_type(8))) short short8;
typedef __attribute__((ext_vector_type(4))) float f32x4;
typedef unsigned short u16;

// fp32 -> bf16 round-to-nearest-even (finite inputs)
__device__ __forceinline__ u16 f2bf(float x) {
    unsigned int u = __float_as_uint(x);
    u += 0x7FFFu + ((u >> 16) & 1u);
    return (u16)(u >> 16);
}

__device__ __forceinline__ void load_lds16(const void* g, void* l) {
    __builtin_amdgcn_global_load_lds(
        (const __attribute__((address_space(1))) unsigned int*)g,
        (__attribute__((address_space(3))) unsigned int*)l,
        16, 0, 0);
}

// ---------------------------------------------------------------------------
// Batched fp32 -> bf16 convert (7 tensors)
// ---------------------------------------------------------------------------
struct CvtArgs {
    const float* src[7];
    u16* dst[7];
    int n8[7];      // element count / 8
};

__global__ __launch_bounds__(256) void cvt_bf16(CvtArgs c) {
    const int z = blockIdx.z;
    const int i = blockIdx.x * 256 + threadIdx.x;
    if (i >= c.n8[z]) return;
    const float4* s = (const float4*)c.src[z];
    const float4 a = s[2 * i];
    const float4 b = s[2 * i + 1];
    union { short8 v; u16 u[8]; } o;
    o.u[0] = f2bf(a.x); o.u[1] = f2bf(a.y); o.u[2] = f2bf(a.z); o.u[3] = f2bf(a.w);
    o.u[4] = f2bf(b.x); o.u[5] = f2bf(b.y); o.u[6] = f2bf(b.z); o.u[7] = f2bf(b.w);
    ((short8*)c.dst[z])[i] = o.v;
}

// ---------------------------------------------------------------------------
// bf16 MFMA GEMM: C[M,N] = A[M,K] @ W[N,K]^T + bias[N]
// m97-style: 128x128 tile, BK=32, 256 threads = 4 waves (2x2 of 64x64),
// global_load_lds width=16 staging, 2-barrier K-loop, fp32 accum.
// z-batched (up to 3 independent GEMMs per launch).
// ---------------------------------------------------------------------------
struct GemmArgs {
    const u16* A[3];
    const u16* W[3];
    const float* bias[3];
    void* C[3];
};

template <bool BF16OUT>
__global__ __launch_bounds__(256) void gemm_nt_mfma(GemmArgs ga, int M, int N, int K)
{
    __shared__ u16 As[128 * 32];
    __shared__ u16 Bs[128 * 32];
    const int z = blockIdx.z;
    const u16* __restrict__ A = ga.A[z];
    const u16* __restrict__ W = ga.W[z];
    const float* __restrict__ bias = ga.bias[z];

    const int tid = threadIdx.x;
    const int w = tid >> 6, l = tid & 63;
    const int l4 = l >> 4, lm = l & 15;
    const int wr = w >> 1, wc = w & 1;
    const int bm = blockIdx.y * 128, bn = blockIdx.x * 128;

    // staging geometry: issue i of wave w covers 1KB = 16 rows of the tile;
    // lane l -> row (w*2+i)*16 + (l>>2), 16B-segment (l&3) within the 64B row.
    const int srow = l >> 2;
    const int sseg = l & 3;

    f32x4 acc[4][4];
#pragma unroll
    for (int m = 0; m < 4; ++m)
#pragma unroll
        for (int n = 0; n < 4; ++n) acc[m][n] = (f32x4){0.f, 0.f, 0.f, 0.f};

    for (int k0 = 0; k0 < K; k0 += 32) {
        __syncthreads();   // previous iter's ds_reads done before overwrite
#pragma unroll
        for (int i = 0; i < 2; ++i) {
            const int blk = w * 2 + i;            // 0..7
            const int row = blk * 16 + srow;      // 0..127
            load_lds16(A + (size_t)(bm + row) * K + k0 + sseg * 8,
                       (char*)As + blk * 1024);
            load_lds16(W + (size_t)(bn + row) * K + k0 + sseg * 8,
                       (char*)Bs + blk * 1024);
        }
        __syncthreads();   // staging visible

        short8 af[4], bf[4];
#pragma unroll
        for (int m = 0; m < 4; ++m)
            af[m] = *(const short8*)&As[(wr * 64 + m * 16 + lm) * 32 + l4 * 8];
#pragma unroll
        for (int n = 0; n < 4; ++n)
            bf[n] = *(const short8*)&Bs[(wc * 64 + n * 16 + lm) * 32 + l4 * 8];
#pragma unroll
        for (int m = 0; m < 4; ++m)
#pragma unroll
            for (int n = 0; n < 4; ++n)
                acc[m][n] = __builtin_amdgcn_mfma_f32_16x16x32_bf16(af[m], bf[n], acc[m][n], 0, 0, 0);
    }

    // epilogue: bias + store. C/D layout: col=lane&15, row=(lane>>4)*4+reg.
    float bv[4];
#pragma unroll
    for (int n = 0; n < 4; ++n) bv[n] = bias[bn + wc * 64 + n * 16 + lm];
#pragma unroll
    for (int m = 0; m < 4; ++m) {
#pragma unroll
        for (int n = 0; n < 4; ++n) {
            const int col = bn + wc * 64 + n * 16 + lm;
#pragma unroll
            for (int r = 0; r < 4; ++r) {
                const int row = bm + wr * 64 + m * 16 + l4 * 4 + r;
                const float v = acc[m][n][r] + bv[n];
                if (BF16OUT)
                    ((u16*)ga.C[z])[(size_t)row * N + col] = f2bf(v);
                else
                    ((float*)ga.C[z])[(size_t)row * N + col] = v;
            }
        }
    }
}

// ---------------------------------------------------------------------------
// MFMA flash attention (bf16 in, fp32 accum, bf16 out).
// Q/K/V layout: [B, S, H*D] bf16; head h = columns h*64 .. h*64+63.
// Block = 256 threads = 4 waves. Q tile = 64 rows (16/wave). KV tile = 64.
// ---------------------------------------------------------------------------
__global__ __launch_bounds__(256) void flash_attn_mfma(
    const u16* __restrict__ Qb, const u16* __restrict__ Kb,
    const u16* __restrict__ Vb, u16* __restrict__ Ob)
{
    __shared__ u16 Ks[64 * 64];
    __shared__ u16 Vt[64 * 64];
    __shared__ u16 Ps[4][16 * 64];

    const int tid = threadIdx.x;
    const int w  = tid >> 6;
    const int l  = tid & 63;
    const int l4 = l >> 4;
    const int lm = l & 15;
    const int s0 = blockIdx.x << 6;
    const int h  = blockIdx.y;
    const int b  = blockIdx.z;
    const size_t bbase = (size_t)b * 2048 * 1024 + (size_t)h * 64;

    short8 qf[2];
    {
        const u16* qrow = Qb + bbase + (size_t)(s0 + w * 16 + lm) * 1024;
        qf[0] = *(const short8*)(qrow + l4 * 8);
        qf[1] = *(const short8*)(qrow + 32 + l4 * 8);
    }

    f32x4 oacc[4];
#pragma unroll
    for (int g = 0; g < 4; ++g) oacc[g] = (f32x4){0.f, 0.f, 0.f, 0.f};
    float m_run[4] = {-1e30f, -1e30f, -1e30f, -1e30f};
    float l_run[4] = {0.f, 0.f, 0.f, 0.f};

    for (int t0 = 0; t0 < 2048; t0 += 64) {
        __syncthreads();
#pragma unroll
        for (int n = 0; n < 2; ++n) {
            const int idx = tid + (n << 8);
            const int row = idx >> 3;
            const int c8  = (idx & 7) << 3;
            const short8 kv = *(const short8*)(Kb + bbase + (size_t)(t0 + row) * 1024 + c8);
            *(short8*)&Ks[(row * 64 + c8) ^ ((row & 7) << 3)] = kv;
            const short8 vv = *(const short8*)(Vb + bbase + (size_t)(t0 + row) * 1024 + c8);
            const u16* vs = (const u16*)&vv;
#pragma unroll
            for (int j = 0; j < 8; ++j) {
                const int d = c8 + j;
                Vt[(d * 64 + row) ^ ((((d & 7) ^ (d >> 3))) << 3)] = vs[j];
            }
        }
        __syncthreads();

        f32x4 sacc[4];
#pragma unroll
        for (int g = 0; g < 4; ++g) sacc[g] = (f32x4){0.f, 0.f, 0.f, 0.f};
#pragma unroll
        for (int g = 0; g < 4; ++g) {
            const int key = lm + 16 * g;
#pragma unroll
            for (int c = 0; c < 2; ++c) {
                const short8 kf = *(const short8*)&Ks[(key * 64 + c * 32 + l4 * 8) ^ ((key & 7) << 3)];
                sacc[g] = __builtin_amdgcn_mfma_f32_16x16x32_bf16(qf[c], kf, sacc[g], 0, 0, 0);
            }
        }

#pragma unroll
        for (int r = 0; r < 4; ++r) {
            float mt = fmaxf(fmaxf(sacc[0][r], sacc[1][r]), fmaxf(sacc[2][r], sacc[3][r]));
            mt = fmaxf(mt, __shfl_xor(mt, 1));
            mt = fmaxf(mt, __shfl_xor(mt, 2));
            mt = fmaxf(mt, __shfl_xor(mt, 4));
            mt = fmaxf(mt, __shfl_xor(mt, 8));
            const float m_new = fmaxf(m_run[r], mt);
            const float alpha = __expf((m_run[r] - m_new) * 0.125f);
            float p[4];
            float ls = 0.f;
#pragma unroll
            for (int g = 0; g < 4; ++g) {
                p[g] = __expf((sacc[g][r] - m_new) * 0.125f);
                ls += p[g];
            }
            const int q = l4 * 4 + r;
#pragma unroll
            for (int g = 0; g < 4; ++g)
                Ps[w][(q * 64 + lm + 16 * g) ^ ((q & 7) << 3)] = f2bf(p[g]);
            ls += __shfl_xor(ls, 1);
            ls += __shfl_xor(ls, 2);
            ls += __shfl_xor(ls, 4);
            ls += __shfl_xor(ls, 8);
            l_run[r] = l_run[r] * alpha + ls;
            m_run[r] = m_new;
#pragma unroll
            for (int g = 0; g < 4; ++g) oacc[g][r] *= alpha;
        }

#pragma unroll
        for (int c = 0; c < 2; ++c) {
            const short8 pa = *(const short8*)&Ps[w][(lm * 64 + c * 32 + l4 * 8) ^ ((lm & 7) << 3)];
#pragma unroll
            for (int g = 0; g < 4; ++g) {
                const int d = lm + 16 * g;
                const short8 vf = *(const short8*)&Vt[(d * 64 + c * 32 + l4 * 8) ^ (((d & 7) ^ (d >> 3)) << 3)];
                oacc[g] = __builtin_amdgcn_mfma_f32_16x16x32_bf16(pa, vf, oacc[g], 0, 0, 0);
            }
        }
    }

#pragma unroll
    for (int r = 0; r < 4; ++r) {
        const float inv = 1.f / l_run[r];
        const size_t qrow = (size_t)(s0 + w * 16 + l4 * 4 + r) * 1024;
#pragma unroll
        for (int g = 0; g < 4; ++g)
            Ob[bbase + qrow + lm + 16 * g] = f2bf(oacc[g][r] * inv);
    }
}

extern "C" void kernel_launch(void* const* d_in, const int* in_sizes, int n_in,
                              void* d_out, int out_size, void* d_ws, size_t ws_size,
                              hipStream_t stream)
{
    // setup_inputs() order: query, value, key, Wq, bq, Wk, bk, Wv, bv, Wo, bo
    const float* query = (const float*)d_in[0];
    const float* value = (const float*)d_in[1];
    const float* key   = (const float*)d_in[2];
    const float* Wq = (const float*)d_in[3];
    const float* bq = (const float*)d_in[4];
    const float* Wk = (const float*)d_in[5];
    const float* bk = (const float*)d_in[6];
    const float* Wv = (const float*)d_in[7];
    const float* bv = (const float*)d_in[8];
    const float* Wo = (const float*)d_in[9];
    const float* bo = (const float*)d_in[10];
    float* out = (float*)d_out;

    const int M = 2 * 2048;      // B*S = 4096
    const int E = 1024;
    const size_t act = (size_t)M * E;      // 4,194,304 elems
    const size_t wel = (size_t)E * E;      // 1,048,576 elems

    // workspace layout (bf16 u16 elements), 64 MiB total
    u16* qc  = (u16*)d_ws;
    u16* kc  = qc + act;
    u16* vc  = kc + act;
    u16* wqb = vc + act;
    u16* wkb = wqb + wel;
    u16* wvb = wkb + wel;
    u16* wob = wvb + wel;
    u16* Qb  = wob + wel;
    u16* Kb  = Qb + act;
    u16* Vb  = Kb + act;
    u16* Ab  = Vb + act;

    // 1) convert inputs to bf16 (batched)
    CvtArgs ca;
    ca.src[0] = query; ca.dst[0] = qc;  ca.n8[0] = (int)(act / 8);
    ca.src[1] = key;   ca.dst[1] = kc;  ca.n8[1] = (int)(act / 8);
    ca.src[2] = value; ca.dst[2] = vc;  ca.n8[2] = (int)(act / 8);
    ca.src[3] = Wq;    ca.dst[3] = wqb; ca.n8[3] = (int)(wel / 8);
    ca.src[4] = Wk;    ca.dst[4] = wkb; ca.n8[4] = (int)(wel / 8);
    ca.src[5] = Wv;    ca.dst[5] = wvb; ca.n8[5] = (int)(wel / 8);
    ca.src[6] = Wo;    ca.dst[6] = wob; ca.n8[6] = (int)(wel / 8);
    dim3 cgrid((unsigned)((act / 8 + 255) / 256), 1, 7);
    hipLaunchKernelGGL(cvt_bf16, cgrid, dim3(256), 0, stream, ca);

    // 2) Q/K/V projections (z-batched bf16 MFMA GEMM)
    GemmArgs gq;
    gq.A[0] = qc; gq.W[0] = wqb; gq.bias[0] = bq; gq.C[0] = Qb;
    gq.A[1] = kc; gq.W[1] = wkb; gq.bias[1] = bk; gq.C[1] = Kb;
    gq.A[2] = vc; gq.W[2] = wvb; gq.bias[2] = bv; gq.C[2] = Vb;
    dim3 ggrid(E / 128, M / 128, 3);
    hipLaunchKernelGGL((gemm_nt_mfma<true>), ggrid, dim3(256), 0, stream, gq, M, E, E);

    // 3) flash attention -> Ab (bf16)
    dim3 fgrid(2048 / 64, 16, 2);
    hipLaunchKernelGGL(flash_attn_mfma, fgrid, dim3(256), 0, stream, Qb, Kb, Vb, Ab);

    // 4) output projection (fp32 out)
    GemmArgs go;
    go.A[0] = Ab; go.W[0] = wob; go.bias[0] = bo; go.C[0] = out;
    go.A[1] = Ab; go.W[1] = wob; go.bias[1] = bo; go.C[1] = out;
    go.A[2] = Ab; go.W[2] = wob; go.bias[2] = bo; go.C[2] = out;
    dim3 ogrid(E / 128, M / 128, 1);
    hipLaunchKernelGGL((gemm_nt_mfma<false>), ogrid, dim3(256), 0, stream, go, M, E, E);
}

// Round 4
// 176.280 us; speedup vs baseline: 11.2998x; 1.2765x over previous
//
#include <hip/hip_runtime.h>
#include <math.h>

// Problem constants: B=2, S=T=2048, E=1024, H=16, D=64
typedef __attribute__((ext_vector_type(8))) short short8;
typedef __attribute__((ext_vector_type(4))) float f32x4;
typedef unsigned short u16;

// fp32 -> bf16 round-to-nearest-even (finite inputs)
__device__ __forceinline__ u16 f2bf(float x) {
    unsigned int u = __float_as_uint(x);
    u += 0x7FFFu + ((u >> 16) & 1u);
    return (u16)(u >> 16);
}

__device__ __forceinline__ void load_lds16(const void* g, void* l) {
    __builtin_amdgcn_global_load_lds(
        (const __attribute__((address_space(1))) unsigned int*)g,
        (__attribute__((address_space(3))) unsigned int*)l,
        16, 0, 0);
}

// ---------------------------------------------------------------------------
// Batched fp32 -> bf16 convert (7 tensors)
// ---------------------------------------------------------------------------
struct CvtArgs {
    const float* src[7];
    u16* dst[7];
    int n8[7];
};

__global__ __launch_bounds__(256) void cvt_bf16(CvtArgs c) {
    const int z = blockIdx.z;
    const int i = blockIdx.x * 256 + threadIdx.x;
    if (i >= c.n8[z]) return;
    const float4* s = (const float4*)c.src[z];
    const float4 a = s[2 * i];
    const float4 b = s[2 * i + 1];
    union { short8 v; u16 u[8]; } o;
    o.u[0] = f2bf(a.x); o.u[1] = f2bf(a.y); o.u[2] = f2bf(a.z); o.u[3] = f2bf(a.w);
    o.u[4] = f2bf(b.x); o.u[5] = f2bf(b.y); o.u[6] = f2bf(b.z); o.u[7] = f2bf(b.w);
    ((short8*)c.dst[z])[i] = o.v;
}

// ---------------------------------------------------------------------------
// bf16 MFMA GEMM: C[M,N] = A[M,K] @ W[N,K]^T + bias[N]  (m97-style, unchanged)
// ---------------------------------------------------------------------------
struct GemmArgs {
    const u16* A[3];
    const u16* W[3];
    const float* bias[3];
    void* C[3];
};

template <bool BF16OUT>
__global__ __launch_bounds__(256) void gemm_nt_mfma(GemmArgs ga, int M, int N, int K)
{
    __shared__ u16 As[128 * 32];
    __shared__ u16 Bs[128 * 32];
    const int z = blockIdx.z;
    const u16* __restrict__ A = ga.A[z];
    const u16* __restrict__ W = ga.W[z];
    const float* __restrict__ bias = ga.bias[z];

    const int tid = threadIdx.x;
    const int w = tid >> 6, l = tid & 63;
    const int l4 = l >> 4, lm = l & 15;
    const int wr = w >> 1, wc = w & 1;
    const int bm = blockIdx.y * 128, bn = blockIdx.x * 128;

    const int srow = l >> 2;
    const int sseg = l & 3;

    f32x4 acc[4][4];
#pragma unroll
    for (int m = 0; m < 4; ++m)
#pragma unroll
        for (int n = 0; n < 4; ++n) acc[m][n] = (f32x4){0.f, 0.f, 0.f, 0.f};

    for (int k0 = 0; k0 < K; k0 += 32) {
        __syncthreads();
#pragma unroll
        for (int i = 0; i < 2; ++i) {
            const int blk = w * 2 + i;
            const int row = blk * 16 + srow;
            load_lds16(A + (size_t)(bm + row) * K + k0 + sseg * 8,
                       (char*)As + blk * 1024);
            load_lds16(W + (size_t)(bn + row) * K + k0 + sseg * 8,
                       (char*)Bs + blk * 1024);
        }
        __syncthreads();

        short8 af[4], bf[4];
#pragma unroll
        for (int m = 0; m < 4; ++m)
            af[m] = *(const short8*)&As[(wr * 64 + m * 16 + lm) * 32 + l4 * 8];
#pragma unroll
        for (int n = 0; n < 4; ++n)
            bf[n] = *(const short8*)&Bs[(wc * 64 + n * 16 + lm) * 32 + l4 * 8];
#pragma unroll
        for (int m = 0; m < 4; ++m)
#pragma unroll
            for (int n = 0; n < 4; ++n)
                acc[m][n] = __builtin_amdgcn_mfma_f32_16x16x32_bf16(af[m], bf[n], acc[m][n], 0, 0, 0);
    }

    float bv[4];
#pragma unroll
    for (int n = 0; n < 4; ++n) bv[n] = bias[bn + wc * 64 + n * 16 + lm];
#pragma unroll
    for (int m = 0; m < 4; ++m) {
#pragma unroll
        for (int n = 0; n < 4; ++n) {
            const int col = bn + wc * 64 + n * 16 + lm;
#pragma unroll
            for (int r = 0; r < 4; ++r) {
                const int row = bm + wr * 64 + m * 16 + l4 * 4 + r;
                const float v = acc[m][n][r] + bv[n];
                if (BF16OUT)
                    ((u16*)ga.C[z])[(size_t)row * N + col] = f2bf(v);
                else
                    ((float*)ga.C[z])[(size_t)row * N + col] = v;
            }
        }
    }
}

// ---------------------------------------------------------------------------
// Flash attention v2: swapped QK^T, QBLK=128 (4 waves x 32 q), KVBLK=64,
// double-buffered K (global_load_lds, pre-swizzled source) and V (reg-staged,
// transposed scalar writes), packed-b64 P roundtrip, defer-rescale.
// All LDS layouts XOR-swizzled to the structural-minimum bank pattern.
//
// mfma_f32_16x16x32_bf16 frags:
//   A: row=lane&15, k=(lane>>4)*8+j   B: col=lane&15, k=(lane>>4)*8+j
//   C/D: col=lane&15, row=(lane>>4)*4+reg   [HW-verified m89]
// QK^T: A=K (row=key), B=Q (col=q)  ->  lane holds S[key=16g+4*l4+r][q=qa*16+lm]
// PV:   A=P (row=q),  B=V^T(col=d)  ->  lane holds O[q=qa*16+4*l4+r][d=16g+lm]
// ---------------------------------------------------------------------------
__global__ __launch_bounds__(256) void flash_attn_mfma2(
    const u16* __restrict__ Qb, const u16* __restrict__ Kb,
    const u16* __restrict__ Vb, u16* __restrict__ Ob)
{
    __shared__ u16 Ks[2][64 * 64];   // [key][d-chunk ^ (key&7)]
    __shared__ u16 Vt[2][64 * 64];   // [d][key-chunk ^ ((d&7)^(d>>3))]
    __shared__ u16 Ps[4][32 * 64];   // per-wave [q][key-chunk4 ^ (2*(q&7))]

    const int tid = threadIdx.x;
    const int w  = tid >> 6;
    const int l  = tid & 63;
    const int l4 = l >> 4;
    const int lm = l & 15;
    const int qb0 = blockIdx.x << 7;
    const int h  = blockIdx.y;
    const int b  = blockIdx.z;
    const size_t bbase = (size_t)b * 2048 * 1024 + (size_t)h * 64;

    // Q fragments (B-operand): qf[qa][c], q = qb0 + w*32 + qa*16 + lm
    short8 qf[2][2];
#pragma unroll
    for (int qa = 0; qa < 2; ++qa) {
        const u16* qrow = Qb + bbase + (size_t)(qb0 + w * 32 + qa * 16 + lm) * 1024;
#pragma unroll
        for (int c = 0; c < 2; ++c)
            qf[qa][c] = *(const short8*)(qrow + c * 32 + l4 * 8);
    }

    short8 vreg[2];

    // K staging: issue i covers keys 8i..8i+7; lane l -> key 8i+(l>>3),
    // source d-chunk pre-swizzled: (l&7) ^ (key&7); LDS dest linear.
    auto stageK = [&](int t0, int bufi) {
#pragma unroll
        for (int ii = 0; ii < 2; ++ii) {
            const int i = w * 2 + ii;
            const int key = i * 8 + (l >> 3);
            const int chunk = (l & 7) ^ ((l >> 3) & 7);
            load_lds16(Kb + bbase + (size_t)(t0 + key) * 1024 + chunk * 8,
                       (char*)&Ks[bufi][0] + i * 1024);
        }
    };
    auto loadV = [&](int t0) {
        const u16* vrow = Vb + bbase + (size_t)(t0 + (tid >> 2)) * 1024 + (tid & 3) * 16;
        vreg[0] = *(const short8*)(vrow);
        vreg[1] = *(const short8*)(vrow + 8);
    };
    auto writeV = [&](int bufi) {
        const int row = tid >> 2;
        const int d0 = (tid & 3) * 16;
        const u16* vr = (const u16*)&vreg[0];
#pragma unroll
        for (int j = 0; j < 16; ++j) {
            const int d = d0 + j;
            Vt[bufi][(d * 64 + row) ^ ((((d & 7) ^ (d >> 3))) << 3)] = vr[j];
        }
    };

    f32x4 oacc[2][4];
#pragma unroll
    for (int qa = 0; qa < 2; ++qa)
#pragma unroll
        for (int g = 0; g < 4; ++g) oacc[qa][g] = (f32x4){0.f, 0.f, 0.f, 0.f};
    float m_run[2] = {-1e30f, -1e30f};
    float l_run[2] = {0.f, 0.f};

    // prologue: stage tile 0
    stageK(0, 0);
    loadV(0);
    writeV(0);
    __syncthreads();

    for (int t = 0; t < 32; ++t) {
        const int buf = t & 1;
        if (t < 31) {           // issue next tile's loads early (T14)
            stageK((t + 1) * 64, buf ^ 1);
            loadV((t + 1) * 64);
        }

        // ---- QK^T (swapped): sacc[qa][g] = K_g . Q_qa ----
        f32x4 sacc[2][4];
#pragma unroll
        for (int qa = 0; qa < 2; ++qa)
#pragma unroll
            for (int g = 0; g < 4; ++g) sacc[qa][g] = (f32x4){0.f, 0.f, 0.f, 0.f};
#pragma unroll
        for (int g = 0; g < 4; ++g) {
#pragma unroll
            for (int c = 0; c < 2; ++c) {
                const short8 kf = *(const short8*)
                    &Ks[buf][(16 * g + lm) * 64 + (((4 * c + l4) ^ (lm & 7)) << 3)];
                sacc[0][g] = __builtin_amdgcn_mfma_f32_16x16x32_bf16(kf, qf[0][c], sacc[0][g], 0, 0, 0);
                sacc[1][g] = __builtin_amdgcn_mfma_f32_16x16x32_bf16(kf, qf[1][c], sacc[1][g], 0, 0, 0);
            }
        }

        // ---- softmax: lane holds 16 scores of row q = qa*16+lm ----
        float mt[2];
#pragma unroll
        for (int qa = 0; qa < 2; ++qa) {
            float a0 = fmaxf(fmaxf(sacc[qa][0][0], sacc[qa][0][1]), fmaxf(sacc[qa][0][2], sacc[qa][0][3]));
            float a1 = fmaxf(fmaxf(sacc[qa][1][0], sacc[qa][1][1]), fmaxf(sacc[qa][1][2], sacc[qa][1][3]));
            float a2 = fmaxf(fmaxf(sacc[qa][2][0], sacc[qa][2][1]), fmaxf(sacc[qa][2][2], sacc[qa][2][3]));
            float a3 = fmaxf(fmaxf(sacc[qa][3][0], sacc[qa][3][1]), fmaxf(sacc[qa][3][2], sacc[qa][3][3]));
            float m0 = fmaxf(fmaxf(a0, a1), fmaxf(a2, a3));
            m0 = fmaxf(m0, __shfl_xor(m0, 16));
            m0 = fmaxf(m0, __shfl_xor(m0, 32));
            mt[qa] = m0;
        }
        const bool resc = !__all((mt[0] <= m_run[0]) && (mt[1] <= m_run[1]));
        if (resc) {
            float alpha[2];
#pragma unroll
            for (int qa = 0; qa < 2; ++qa) {
                const float mn = fmaxf(m_run[qa], mt[qa]);
                alpha[qa] = __expf(0.125f * (m_run[qa] - mn));
                m_run[qa] = mn;
                l_run[qa] *= alpha[qa];
            }
#pragma unroll
            for (int qa = 0; qa < 2; ++qa)
#pragma unroll
                for (int r = 0; r < 4; ++r) {
                    const float a = __shfl(alpha[qa], l4 * 4 + r);
#pragma unroll
                    for (int g = 0; g < 4; ++g) oacc[qa][g][r] *= a;
                }
        }
        // P = exp(0.125*(S - m)), pack 4 consecutive keys -> b64 writes
#pragma unroll
        for (int qa = 0; qa < 2; ++qa) {
            float lsum = 0.f;
            const float mr = m_run[qa];
#pragma unroll
            for (int g = 0; g < 4; ++g) {
                const float p0 = __expf(0.125f * (sacc[qa][g][0] - mr));
                const float p1 = __expf(0.125f * (sacc[qa][g][1] - mr));
                const float p2 = __expf(0.125f * (sacc[qa][g][2] - mr));
                const float p3 = __expf(0.125f * (sacc[qa][g][3] - mr));
                lsum += (p0 + p1) + (p2 + p3);
                ushort4 pk;
                pk.x = f2bf(p0); pk.y = f2bf(p1); pk.z = f2bf(p2); pk.w = f2bf(p3);
                *(ushort4*)&Ps[w][(qa * 16 + lm) * 64 + (((g * 4 + l4) ^ ((lm & 7) << 1)) << 2)] = pk;
            }
            lsum += __shfl_xor(lsum, 16);
            lsum += __shfl_xor(lsum, 32);
            l_run[qa] += lsum;
        }

        // ---- PV: oacc[qa][g] += P_qa . V^T_g ----
#pragma unroll
        for (int c = 0; c < 2; ++c) {
            short8 pa[2];
#pragma unroll
            for (int qa = 0; qa < 2; ++qa)
                pa[qa] = *(const short8*)
                    &Ps[w][(qa * 16 + lm) * 64 + (((c * 8 + l4 * 2) ^ ((lm & 7) << 1)) << 2)];
#pragma unroll
            for (int g = 0; g < 4; ++g) {
                const int d = g * 16 + lm;
                const short8 vf = *(const short8*)
                    &Vt[buf][(d * 64 + c * 32 + l4 * 8) ^ ((((d & 7) ^ (d >> 3))) << 3)];
                oacc[0][g] = __builtin_amdgcn_mfma_f32_16x16x32_bf16(pa[0], vf, oacc[0][g], 0, 0, 0);
                oacc[1][g] = __builtin_amdgcn_mfma_f32_16x16x32_bf16(pa[1], vf, oacc[1][g], 0, 0, 0);
            }
        }

        if (t < 31) writeV(buf ^ 1);   // late write: HBM latency hidden under compute
        __syncthreads();
    }

    // ---- epilogue ----
#pragma unroll
    for (int qa = 0; qa < 2; ++qa) {
#pragma unroll
        for (int r = 0; r < 4; ++r) {
            const float linv = 1.f / __shfl(l_run[qa], l4 * 4 + r);
            const size_t orow = bbase + (size_t)(qb0 + w * 32 + qa * 16 + l4 * 4 + r) * 1024;
#pragma unroll
            for (int g = 0; g < 4; ++g)
                Ob[orow + g * 16 + lm] = f2bf(oacc[qa][g][r] * linv);
        }
    }
}

extern "C" void kernel_launch(void* const* d_in, const int* in_sizes, int n_in,
                              void* d_out, int out_size, void* d_ws, size_t ws_size,
                              hipStream_t stream)
{
    const float* query = (const float*)d_in[0];
    const float* value = (const float*)d_in[1];
    const float* key   = (const float*)d_in[2];
    const float* Wq = (const float*)d_in[3];
    const float* bq = (const float*)d_in[4];
    const float* Wk = (const float*)d_in[5];
    const float* bk = (const float*)d_in[6];
    const float* Wv = (const float*)d_in[7];
    const float* bv = (const float*)d_in[8];
    const float* Wo = (const float*)d_in[9];
    const float* bo = (const float*)d_in[10];
    float* out = (float*)d_out;

    const int M = 2 * 2048;
    const int E = 1024;
    const size_t act = (size_t)M * E;
    const size_t wel = (size_t)E * E;

    u16* qc  = (u16*)d_ws;
    u16* kc  = qc + act;
    u16* vc  = kc + act;
    u16* wqb = vc + act;
    u16* wkb = wqb + wel;
    u16* wvb = wkb + wel;
    u16* wob = wvb + wel;
    u16* Qb  = wob + wel;
    u16* Kb  = Qb + act;
    u16* Vb  = Kb + act;
    u16* Ab  = Vb + act;

    CvtArgs ca;
    ca.src[0] = query; ca.dst[0] = qc;  ca.n8[0] = (int)(act / 8);
    ca.src[1] = key;   ca.dst[1] = kc;  ca.n8[1] = (int)(act / 8);
    ca.src[2] = value; ca.dst[2] = vc;  ca.n8[2] = (int)(act / 8);
    ca.src[3] = Wq;    ca.dst[3] = wqb; ca.n8[3] = (int)(wel / 8);
    ca.src[4] = Wk;    ca.dst[4] = wkb; ca.n8[4] = (int)(wel / 8);
    ca.src[5] = Wv;    ca.dst[5] = wvb; ca.n8[5] = (int)(wel / 8);
    ca.src[6] = Wo;    ca.dst[6] = wob; ca.n8[6] = (int)(wel / 8);
    dim3 cgrid((unsigned)((act / 8 + 255) / 256), 1, 7);
    hipLaunchKernelGGL(cvt_bf16, cgrid, dim3(256), 0, stream, ca);

    GemmArgs gq;
    gq.A[0] = qc; gq.W[0] = wqb; gq.bias[0] = bq; gq.C[0] = Qb;
    gq.A[1] = kc; gq.W[1] = wkb; gq.bias[1] = bk; gq.C[1] = Kb;
    gq.A[2] = vc; gq.W[2] = wvb; gq.bias[2] = bv; gq.C[2] = Vb;
    dim3 ggrid(E / 128, M / 128, 3);
    hipLaunchKernelGGL((gemm_nt_mfma<true>), ggrid, dim3(256), 0, stream, gq, M, E, E);

    dim3 fgrid(2048 / 128, 16, 2);
    hipLaunchKernelGGL(flash_attn_mfma2, fgrid, dim3(256), 0, stream, Qb, Kb, Vb, Ab);

    GemmArgs go;
    go.A[0] = Ab; go.W[0] = wob; go.bias[0] = bo; go.C[0] = out;
    go.A[1] = Ab; go.W[1] = wob; go.bias[1] = bo; go.C[1] = out;
    go.A[2] = Ab; go.W[2] = wob; go.bias[2] = bo; go.C[2] = out;
    dim3 ogrid(E / 128, M / 128, 1);
    hipLaunchKernelGGL((gemm_nt_mfma<false>), ogrid, dim3(256), 0, stream, go, M, E, E);
}